// Round 7
// baseline (473.056 us; speedup 1.0000x reference)
//
#include <hip/hip_runtime.h>

// SimpleNet R7: R6's algorithm (MFMA f16 matmuls + Eigen rational tanh +
// sigmoid = 0.5+0.5*tanh(y/2)) with codegen FORCED:
//  - v_pk_fma_f32 / v_pk_mul_f32 via inline asm (R6's <2 x float> scalarized)
//  - poly constants pinned in VGPRs once via empty-asm (R6 rematerialized
//    v_movs per eval: ~2300 extra cyc/wave-iter)
//  - reciprocal = bit-trick seed + 2 Newton on the FMA pipe (no v_rcp)
// MFMA layout unchanged from R5/R6 (validated: absmax at bf16 floor).

#define HW_PIX (1024 * 1024)
#define HID    25

typedef __fp16 h8 __attribute__((ext_vector_type(8)));
typedef __fp16 h2 __attribute__((ext_vector_type(2)));
typedef float f32x4 __attribute__((ext_vector_type(4)));
typedef float f2 __attribute__((ext_vector_type(2)));

#define WS_WINP_BYTE 13312

__device__ __forceinline__ int mu_map(int k) {
    int g = k >> 3, j = k & 7;
    return (j < 4) ? (4 * g + j) : (16 + 4 * g + (j & 3));
}

__global__ __launch_bounds__(256) void prep_kernel(
    const float* __restrict__ w_in, const float* __restrict__ ws,
    const float* __restrict__ w_out, __fp16* __restrict__ wsA,
    float* __restrict__ winp)
{
    int tid = threadIdx.x;
    for (int u = tid; u < 12 * 64; u += 256) {
        int q = u & 63, combo = u >> 6;
        int l = combo >> 1, t = combo & 1;
        int m = t * 16 + (q & 15);
        for (int j = 0; j < 8; ++j) {
            int k = (q >> 4) * 8 + j;
            int c = mu_map(k);
            float v = (m < HID && c < HID) ? ws[(l * HID + m) * HID + c] : 0.0f;
            wsA[u * 8 + j] = (__fp16)v;
        }
    }
    if (tid < 64) {
        int q = tid, m = q & 15;
        for (int j = 0; j < 8; ++j) {
            int k = (q >> 4) * 8 + j;
            int c = mu_map(k);
            float v = (m < 3 && c < HID) ? w_out[m * HID + c] * 0.5f : 0.0f;
            wsA[(12 * 64 + q) * 8 + j] = (__fp16)v;
        }
    }
    if (tid < 32) {
        int k = tid, c = mu_map(k);
        for (int ci = 0; ci < 3; ++ci)
            winp[k * 3 + ci] = (c < HID) ? w_in[c * 3 + ci] : 0.0f;
    }
}

// ---- guaranteed-packed fp32 ops (VOP3P) ----
__device__ __forceinline__ f2 pk_fma(f2 a, f2 b, f2 c) {
    f2 d;
    asm("v_pk_fma_f32 %0, %1, %2, %3" : "=v"(d) : "v"(a), "v"(b), "v"(c));
    return d;
}
__device__ __forceinline__ f2 pk_mul(f2 a, f2 b) {
    f2 d;
    asm("v_pk_mul_f32 %0, %1, %2" : "=v"(d) : "v"(a), "v"(b));
    return d;
}

struct TK {
    f2 a13, a11, a9, a7, a5, a3, a1, b6, b4, b2, b0, two;
    float C, nC;
};

__device__ __forceinline__ TK make_tk() {
    TK k;
    k.a13 = (f2)(-2.76076847742355e-16f);
    k.a11 = (f2)(2.00018790482477e-13f);
    k.a9  = (f2)(-8.60467152213735e-11f);
    k.a7  = (f2)(5.12229709037114e-08f);
    k.a5  = (f2)(1.48572235717979e-05f);
    k.a3  = (f2)(6.37261928875436e-04f);
    k.a1  = (f2)(4.89352455891786e-03f);
    k.b6  = (f2)(1.19825839466702e-06f);
    k.b4  = (f2)(1.18534705686654e-04f);
    k.b2  = (f2)(2.26843463243900e-03f);
    k.b0  = (f2)(4.89352518554385e-03f);
    k.two = (f2)(2.0f);
    k.C   = 7.90531110763549805f;
    k.nC  = -7.90531110763549805f;
    // pin in VGPRs: opaque to constant-folding / rematerialization
    asm("" : "+v"(k.a13), "+v"(k.a11), "+v"(k.a9), "+v"(k.a7), "+v"(k.a5));
    asm("" : "+v"(k.a3), "+v"(k.a1), "+v"(k.b6), "+v"(k.b4), "+v"(k.b2));
    asm("" : "+v"(k.b0), "+v"(k.two), "+v"(k.C), "+v"(k.nC));
    return k;
}

// Eigen ptanh rational, 2 evals per call, all on the full-rate FMA pipe.
__device__ __forceinline__ f2 tanh_pk2(f2 z, const TK& k) {
    f2 x;
    x.x = __builtin_amdgcn_fmed3f(z.x, k.nC, k.C);
    x.y = __builtin_amdgcn_fmed3f(z.y, k.nC, k.C);
    f2 s = pk_mul(x, x);
    f2 p = pk_fma(k.a13, s, k.a11);
    p = pk_fma(p, s, k.a9);
    p = pk_fma(p, s, k.a7);
    p = pk_fma(p, s, k.a5);
    p = pk_fma(p, s, k.a3);
    p = pk_fma(p, s, k.a1);
    p = pk_mul(p, x);
    f2 q = pk_fma(k.b6, s, k.b4);
    q = pk_fma(q, s, k.b2);
    q = pk_fma(q, s, k.b0);
    // rcp(q): bit-trick seed + 2 Newton (q in [0.0049, 0.92], positive)
    union { float f; unsigned u; } s0, s1;
    s0.f = q.x; s1.f = q.y;
    s0.u = 0x7EF311C3u - s0.u;
    s1.u = 0x7EF311C3u - s1.u;
    f2 y; y.x = s0.f; y.y = s1.f;
    f2 nq = -q;
    f2 t = pk_fma(nq, y, k.two);
    y = pk_mul(y, t);
    t = pk_fma(nq, y, k.two);
    y = pk_mul(y, t);
    return pk_mul(p, y);
}

__device__ __forceinline__ void tanh4(float a, float b, float c, float d,
                                      const TK& k, h2* o0, h2* o1) {
    f2 z0; z0.x = a; z0.y = b;
    f2 z1; z1.x = c; z1.y = d;
    f2 t0 = tanh_pk2(z0, k);
    f2 t1 = tanh_pk2(z1, k);
    *o0 = __builtin_amdgcn_cvt_pkrtz(t0.x, t0.y);
    *o1 = __builtin_amdgcn_cvt_pkrtz(t1.x, t1.y);
}

__global__ __launch_bounds__(256, 1) void simplenet_kernel(
    const float* __restrict__ x,
    const h8* __restrict__ wsA,
    const float* __restrict__ winp,
    float* __restrict__ out)
{
    const int lane = threadIdx.x & 63;
    const int wgid = blockIdx.x * 4 + (threadIdx.x >> 6);
    const int g = lane >> 4, col = lane & 15;

    const TK k = make_tk();

    h8 A[12];
#pragma unroll
    for (int i = 0; i < 12; ++i) A[i] = wsA[i * 64 + lane];
    h8 Aout = wsA[12 * 64 + lane];

    float wi[24];
    {
        const f32x4* wp4 = (const f32x4*)(winp + 8 * g * 3);
#pragma unroll
        for (int i = 0; i < 6; ++i) {
            f32x4 v = wp4[i];
            wi[i * 4 + 0] = v.x; wi[i * 4 + 1] = v.y; wi[i * 4 + 2] = v.z; wi[i * 4 + 3] = v.w;
        }
    }

    const int pbase = wgid * 512;
    const int b = pbase >> 20;
    const int hwb = pbase & (HW_PIX - 1);
    const float* xb = x + (size_t)b * 3 * HW_PIX;
    float* ob = out + (size_t)b * 3 * HW_PIX;

    for (int it = 0; it < 16; ++it) {
        const int hw0 = hwb + it * 32;

        // ---- input layer ----
        h8 B[2];
#pragma unroll
        for (int n = 0; n < 2; ++n) {
            const int hw = hw0 + n * 16 + col;
            float x0 = xb[0 * HW_PIX + hw];
            float x1 = xb[1 * HW_PIX + hw];
            float x2 = xb[2 * HW_PIX + hw];
            float th[8];
#pragma unroll
            for (int j = 0; j < 8; ++j) {
                float acc = wi[j * 3 + 0] * x0;
                acc = fmaf(wi[j * 3 + 1], x1, acc);
                acc = fmaf(wi[j * 3 + 2], x2, acc);
                th[j] = acc;
            }
            union { h8 v; h2 p[4]; } u;
            tanh4(th[0], th[1], th[2], th[3], k, &u.p[0], &u.p[1]);
            tanh4(th[4], th[5], th[6], th[7], k, &u.p[2], &u.p[3]);
            B[n] = u.v;
        }

        // ---- 6 hidden layers ----
#pragma unroll
        for (int l = 0; l < 6; ++l) {
#pragma unroll
            for (int n = 0; n < 2; ++n) {
                f32x4 zero = {0.0f, 0.0f, 0.0f, 0.0f};
                f32x4 d0 = __builtin_amdgcn_mfma_f32_16x16x32_f16(A[l * 2 + 0], B[n], zero, 0, 0, 0);
                f32x4 d1 = __builtin_amdgcn_mfma_f32_16x16x32_f16(A[l * 2 + 1], B[n], zero, 0, 0, 0);
                union { h8 v; h2 p[4]; } u;
                tanh4(d0.x, d0.y, d0.z, d0.w, k, &u.p[0], &u.p[1]);
                tanh4(d1.x, d1.y, d1.z, d1.w, k, &u.p[2], &u.p[3]);
                B[n] = u.v;
            }
        }

        // ---- output layer: sigmoid via pre-halved w_out + tanh ----
#pragma unroll
        for (int n = 0; n < 2; ++n) {
            f32x4 zero = {0.0f, 0.0f, 0.0f, 0.0f};
            f32x4 d = __builtin_amdgcn_mfma_f32_16x16x32_f16(Aout, B[n], zero, 0, 0, 0);
            if (g == 0) {
                f2 p0; p0.x = d.x; p0.y = d.y;
                f2 t0 = tanh_pk2(p0, k);
                f2 p1; p1.x = d.z; p1.y = d.z;
                f2 t1 = tanh_pk2(p1, k);
                const int hw = hw0 + n * 16 + col;
                ob[0 * HW_PIX + hw] = fmaf(0.5f, t0.x, 0.5f);
                ob[1 * HW_PIX + hw] = fmaf(0.5f, t0.y, 0.5f);
                ob[2 * HW_PIX + hw] = fmaf(0.5f, t1.x, 0.5f);
            }
        }
    }
}

extern "C" void kernel_launch(void* const* d_in, const int* in_sizes, int n_in,
                              void* d_out, int out_size, void* d_ws, size_t ws_size,
                              hipStream_t stream) {
    const float* x     = (const float*)d_in[0];
    const float* w_in  = (const float*)d_in[1];
    const float* ws    = (const float*)d_in[2];
    const float* w_out = (const float*)d_in[3];
    float* out         = (float*)d_out;

    __fp16* wsA = (__fp16*)d_ws;
    float* winp = (float*)((char*)d_ws + WS_WINP_BYTE);

    hipLaunchKernelGGL(prep_kernel, dim3(1), dim3(256), 0, stream,
                       w_in, ws, w_out, wsA, winp);

    hipLaunchKernelGGL(simplenet_kernel, dim3(2048), dim3(256), 0, stream,
                       x, (const h8*)d_ws, winp, out);
}

// Round 8
// 357.772 us; speedup vs baseline: 1.3222x; 1.3222x over previous
//
#include <hip/hip_runtime.h>

// SimpleNet R8: MFMA f16 matmuls (R5 layout, validated) + PACKED-FP16 Padé tanh.
// Model revision (R7 post-mortem): fp32 pk is HALF-rate on CDNA4 (157 TF is the
// scalar rate); the only 2x packed pipe is v_pk_*_f16. So evaluate tanh in h2:
//   tanh x = x(s^2+105s+945)/(15s^2+420s+945), s=x^2, clamp |x|<=3.625
// (continued-fraction Pade(5,4); max err ~1.3e-3). Division = fp16 bit-trick
// seed (0x7799 - bits) + 2 packed Newton. 14 pk ops / 2 evals = ~14 cyc/eval
// vs R5's ~34. Sigmoid = 0.5 + 0.5*tanh(y/2), 0.5 folded into w_out (prep).

#define HW_PIX (1024 * 1024)
#define HID    25

typedef __fp16 h8 __attribute__((ext_vector_type(8)));
typedef __fp16 h2 __attribute__((ext_vector_type(2)));
typedef short  s2 __attribute__((ext_vector_type(2)));
typedef float  f32x4 __attribute__((ext_vector_type(4)));

#define WS_WINP_BYTE 13312

__device__ __forceinline__ int mu_map(int k) {
    int g = k >> 3, j = k & 7;
    return (j < 4) ? (4 * g + j) : (16 + 4 * g + (j & 3));
}

__global__ __launch_bounds__(256) void prep_kernel(
    const float* __restrict__ w_in, const float* __restrict__ ws,
    const float* __restrict__ w_out, __fp16* __restrict__ wsA,
    float* __restrict__ winp)
{
    int tid = threadIdx.x;
    for (int u = tid; u < 12 * 64; u += 256) {
        int q = u & 63, combo = u >> 6;
        int l = combo >> 1, t = combo & 1;
        int m = t * 16 + (q & 15);
        for (int j = 0; j < 8; ++j) {
            int k = (q >> 4) * 8 + j;
            int c = mu_map(k);
            float v = (m < HID && c < HID) ? ws[(l * HID + m) * HID + c] : 0.0f;
            wsA[u * 8 + j] = (__fp16)v;
        }
    }
    if (tid < 64) {
        int q = tid, m = q & 15;
        for (int j = 0; j < 8; ++j) {
            int k = (q >> 4) * 8 + j;
            int c = mu_map(k);
            float v = (m < 3 && c < HID) ? w_out[m * HID + c] * 0.5f : 0.0f;
            wsA[(12 * 64 + q) * 8 + j] = (__fp16)v;
        }
    }
    if (tid < 32) {
        int k = tid, c = mu_map(k);
        for (int ci = 0; ci < 3; ++ci)
            winp[k * 3 + ci] = (c < HID) ? w_in[c * 3 + ci] : 0.0f;
    }
}

// fp16 tanh constants, pinned in VGPRs once (avoid per-eval remat: R6 lesson)
struct HK {
    h2 C, nC, c105, c945, c15, c420, two;
    s2 magic;
};
__device__ __forceinline__ HK make_hk() {
    HK k;
    k.C    = (h2)(__fp16)3.625f;
    k.nC   = (h2)(__fp16)(-3.625f);
    k.c105 = (h2)(__fp16)105.0f;
    k.c945 = (h2)(__fp16)945.0f;
    k.c15  = (h2)(__fp16)15.0f;
    k.c420 = (h2)(__fp16)420.0f;
    k.two  = (h2)(__fp16)2.0f;
    k.magic = (s2)(short)0x7799;
    asm("" : "+v"(k.C), "+v"(k.nC), "+v"(k.c105), "+v"(k.c945));
    asm("" : "+v"(k.c15), "+v"(k.c420), "+v"(k.two), "+v"(k.magic));
    return k;
}

// packed fp16 tanh: 2 evals per call, all v_pk_*_f16 (full-rate pipe)
__device__ __forceinline__ h2 tanh_h2(h2 z, const HK& k) {
    h2 x = __builtin_elementwise_max(z, k.nC);
    x = __builtin_elementwise_min(x, k.C);
    h2 s = x * x;
    h2 n = __builtin_elementwise_fma(s + k.c105, s, k.c945);
    n = n * x;                                             // num = x(s^2+105s+945)
    h2 d = __builtin_elementwise_fma(k.c15, s, k.c420);
    d = __builtin_elementwise_fma(d, s, k.c945);           // den = 15s^2+420s+945
    union { h2 h; s2 i; } du, yu;
    du.h = d;
    yu.i = k.magic - du.i;                                 // rcp seed (den > 0)
    h2 y = yu.h;
    h2 t = __builtin_elementwise_fma(-d, y, k.two);        // 2 Newton iters
    y = y * t;
    t = __builtin_elementwise_fma(-d, y, k.two);
    y = y * t;
    return n * y;
}

__global__ __launch_bounds__(256, 1) void simplenet_kernel(
    const float* __restrict__ x,
    const h8* __restrict__ wsA,
    const float* __restrict__ winp,
    float* __restrict__ out)
{
    const int lane = threadIdx.x & 63;
    const int wgid = blockIdx.x * 4 + (threadIdx.x >> 6);
    const int g = lane >> 4, col = lane & 15;

    const HK k = make_hk();

    h8 A[12];
#pragma unroll
    for (int i = 0; i < 12; ++i) A[i] = wsA[i * 64 + lane];
    h8 Aout = wsA[12 * 64 + lane];

    float wi[24];
    {
        const f32x4* wp4 = (const f32x4*)(winp + 8 * g * 3);
#pragma unroll
        for (int i = 0; i < 6; ++i) {
            f32x4 v = wp4[i];
            wi[i * 4 + 0] = v.x; wi[i * 4 + 1] = v.y; wi[i * 4 + 2] = v.z; wi[i * 4 + 3] = v.w;
        }
    }

    const int pbase = wgid * 512;
    const int b = pbase >> 20;
    const int hwb = pbase & (HW_PIX - 1);
    const float* xb = x + (size_t)b * 3 * HW_PIX;
    float* ob = out + (size_t)b * 3 * HW_PIX;

    for (int it = 0; it < 16; ++it) {
        const int hw0 = hwb + it * 32;

        // ---- input layer: fp32 fma (3 terms), pack pre-acts, packed tanh ----
        h8 B[2];
#pragma unroll
        for (int n = 0; n < 2; ++n) {
            const int hw = hw0 + n * 16 + col;
            float x0 = xb[0 * HW_PIX + hw];
            float x1 = xb[1 * HW_PIX + hw];
            float x2 = xb[2 * HW_PIX + hw];
            float th[8];
#pragma unroll
            for (int j = 0; j < 8; ++j) {
                float acc = wi[j * 3 + 0] * x0;
                acc = fmaf(wi[j * 3 + 1], x1, acc);
                acc = fmaf(wi[j * 3 + 2], x2, acc);
                th[j] = acc;
            }
            union { h8 v; h2 p[4]; } u;
#pragma unroll
            for (int pr = 0; pr < 4; ++pr)
                u.p[pr] = tanh_h2(__builtin_amdgcn_cvt_pkrtz(th[pr * 2], th[pr * 2 + 1]), k);
            B[n] = u.v;
        }

        // ---- 6 hidden layers: MFMA -> pack pre-acts -> packed tanh -> B ----
#pragma unroll
        for (int l = 0; l < 6; ++l) {
#pragma unroll
            for (int n = 0; n < 2; ++n) {
                f32x4 zero = {0.0f, 0.0f, 0.0f, 0.0f};
                f32x4 d0 = __builtin_amdgcn_mfma_f32_16x16x32_f16(A[l * 2 + 0], B[n], zero, 0, 0, 0);
                f32x4 d1 = __builtin_amdgcn_mfma_f32_16x16x32_f16(A[l * 2 + 1], B[n], zero, 0, 0, 0);
                union { h8 v; h2 p[4]; } u;
                u.p[0] = tanh_h2(__builtin_amdgcn_cvt_pkrtz(d0.x, d0.y), k);
                u.p[1] = tanh_h2(__builtin_amdgcn_cvt_pkrtz(d0.z, d0.w), k);
                u.p[2] = tanh_h2(__builtin_amdgcn_cvt_pkrtz(d1.x, d1.y), k);
                u.p[3] = tanh_h2(__builtin_amdgcn_cvt_pkrtz(d1.z, d1.w), k);
                B[n] = u.v;
            }
        }

        // ---- output: sigmoid via pre-halved w_out + packed tanh ----
#pragma unroll
        for (int n = 0; n < 2; ++n) {
            f32x4 zero = {0.0f, 0.0f, 0.0f, 0.0f};
            f32x4 d = __builtin_amdgcn_mfma_f32_16x16x32_f16(Aout, B[n], zero, 0, 0, 0);
            if (g == 0) {
                h2 ta = tanh_h2(__builtin_amdgcn_cvt_pkrtz(d.x, d.y), k);
                h2 tb = tanh_h2(__builtin_amdgcn_cvt_pkrtz(d.z, d.z), k);
                const int hw = hw0 + n * 16 + col;
                ob[0 * HW_PIX + hw] = fmaf(0.5f, (float)ta.x, 0.5f);
                ob[1 * HW_PIX + hw] = fmaf(0.5f, (float)ta.y, 0.5f);
                ob[2 * HW_PIX + hw] = fmaf(0.5f, (float)tb.x, 0.5f);
            }
        }
    }
}

extern "C" void kernel_launch(void* const* d_in, const int* in_sizes, int n_in,
                              void* d_out, int out_size, void* d_ws, size_t ws_size,
                              hipStream_t stream) {
    const float* x     = (const float*)d_in[0];
    const float* w_in  = (const float*)d_in[1];
    const float* ws    = (const float*)d_in[2];
    const float* w_out = (const float*)d_in[3];
    float* out         = (float*)d_out;

    __fp16* wsA = (__fp16*)d_ws;
    float* winp = (float*)((char*)d_ws + WS_WINP_BYTE);

    hipLaunchKernelGGL(prep_kernel, dim3(1), dim3(256), 0, stream,
                       w_in, ws, w_out, wsA, winp);

    hipLaunchKernelGGL(simplenet_kernel, dim3(2048), dim3(256), 0, stream,
                       x, (const h8*)d_ws, winp, out);
}